// Round 2
// baseline (305.709 us; speedup 1.0000x reference)
//
#include <hip/hip_runtime.h>
#include <hip/hip_bf16.h>

#define D_IN  2048
#define D_OUT 2048
#define RNK   64
#define NE    16
#define KTOT  3072   // D_IN + NE*RNK

typedef __attribute__((ext_vector_type(8))) short bf16x8;
typedef __attribute__((ext_vector_type(4))) float f32x4;

__device__ __forceinline__ void async_ld16(const void* g, void* l) {
    __builtin_amdgcn_global_load_lds(
        (const __attribute__((address_space(1))) void*)g,
        (__attribute__((address_space(3))) void*)l,
        16, 0, 0);
}

// ---------------------------------------------------------------------------
// K1: merged weight prep.
//  blocks [0,2048):   Wc row n = [ W_base | B' ], B'[n][e*64+r] = B[e][n][r]
//  blocks [2048,2112): Ab row r = bf16(A[r])  (parked in d_out)
// ---------------------------------------------------------------------------
__global__ __launch_bounds__(384) void castwa_kernel(
    const float* __restrict__ Wb, const float* __restrict__ Bm,
    const float* __restrict__ A,
    __hip_bfloat16* __restrict__ Wc, __hip_bfloat16* __restrict__ Ab)
{
    const int c = threadIdx.x * 8;
    const float* src;
    __hip_bfloat16* dst;
    if (blockIdx.x < D_OUT) {
        const int n = blockIdx.x;
        if (c < D_IN) {
            src = Wb + (size_t)n * D_IN + c;
        } else {
            const int j = c - D_IN;
            const int e = j >> 6, r = j & 63;
            src = Bm + ((size_t)e * D_OUT + n) * RNK + r;
        }
        dst = Wc + (size_t)n * KTOT + c;
    } else {
        if (c >= D_IN) return;
        const int r = blockIdx.x - D_OUT;
        src = A + (size_t)r * D_IN + c;
        dst = Ab + (size_t)r * D_IN + c;
    }
    const float4 a = *(const float4*)src;
    const float4 b = *(const float4*)(src + 4);
    const float vv[8] = {a.x, a.y, a.z, a.w, b.x, b.y, b.z, b.w};
    union { bf16x8 v; __hip_bfloat16 h[8]; } u;
#pragma unroll
    for (int q = 0; q < 8; ++q) u.h[q] = __float2bfloat16(vv[q]);
    *(bf16x8*)dst = u.v;
}

// ---------------------------------------------------------------------------
// K2: prep — bf16(x) emit + fp32 router logits + softmax/top-k -> wfin.
// W_router K-chunks staged into LDS once per block (double-buffered async
// global_load_lds). Router math fp32 so top-k matches reference.
// ---------------------------------------------------------------------------
__global__ __launch_bounds__(256) void prep_kernel(
    const float* __restrict__ x, const float* __restrict__ Wr,
    const int* __restrict__ topk_p, __hip_bfloat16* __restrict__ Xc,
    float* __restrict__ wfin)
{
    __shared__ __align__(16) float wr_lds[2][NE * 256];   // 2 x 16 KB
    const int tid = threadIdx.x;
    const int wave = tid >> 6, lane = tid & 63;
    const int t0 = blockIdx.x * 8 + wave * 2;   // 2 tokens per wave

    float acc[NE][2];
#pragma unroll
    for (int e = 0; e < NE; ++e) { acc[e][0] = 0.f; acc[e][1] = 0.f; }

    const float4* x4 = (const float4*)x;

    auto stage = [&](int buf, int i) {
#pragma unroll
        for (int j = 0; j < 4; ++j) {
            const int r = wave * 4 + j;
            async_ld16(Wr + (size_t)r * D_IN + i * 256 + lane * 4,
                       (void*)&wr_lds[buf][r * 256]);
        }
    };

    stage(0, 0);
    __syncthreads();                             // chunk 0 staged

#pragma unroll
    for (int i = 0; i < 8; ++i) {                // K chunks of 256 floats
        if (i < 7) stage((i + 1) & 1, i + 1);    // async prefetch next chunk

        float4 xv[2];
#pragma unroll
        for (int t = 0; t < 2; ++t) {
            xv[t] = x4[(size_t)(t0 + t) * 512 + i * 64 + lane];
            union { short4 v; __hip_bfloat16 h[4]; } u;
            u.h[0] = __float2bfloat16(xv[t].x); u.h[1] = __float2bfloat16(xv[t].y);
            u.h[2] = __float2bfloat16(xv[t].z); u.h[3] = __float2bfloat16(xv[t].w);
            *(short4*)(Xc + (size_t)(t0 + t) * KTOT + (i * 64 + lane) * 4) = u.v;
        }

        const float4* wr4 = (const float4*)wr_lds[i & 1];
#pragma unroll
        for (int e = 0; e < NE; ++e) {
            const float4 wv = wr4[e * 64 + lane];
#pragma unroll
            for (int t = 0; t < 2; ++t)
                acc[e][t] += xv[t].x * wv.x + xv[t].y * wv.y
                           + xv[t].z * wv.z + xv[t].w * wv.w;
        }
        __syncthreads();   // drains prefetch + guards buffer reuse
    }

#pragma unroll
    for (int off = 32; off; off >>= 1)
#pragma unroll
        for (int e = 0; e < NE; ++e)
#pragma unroll
            for (int t = 0; t < 2; ++t)
                acc[e][t] += __shfl_xor(acc[e][t], off, 64);

    if (lane < 2) {
        const int tt = lane;
        const int k = topk_p[0];
        float m = -1e30f;
#pragma unroll
        for (int e = 0; e < NE; ++e) m = fmaxf(m, acc[e][tt]);
        float w[NE]; float ssum = 0.f;
#pragma unroll
        for (int e = 0; e < NE; ++e) { w[e] = __expf(acc[e][tt] - m); ssum += w[e]; }
        const float inv = 1.f / ssum;
#pragma unroll
        for (int e = 0; e < NE; ++e) w[e] *= inv;
        float* wfout = wfin + (size_t)(t0 + tt) * NE;
        if (k > 0 && k < NE) {
            int chosen[NE];
#pragma unroll
            for (int e = 0; e < NE; ++e) chosen[e] = 0;
            float ksum = 0.f;
            for (int it = 0; it < k; ++it) {
                int bi = 0; float bv = -1.f;
                for (int e = 0; e < NE; ++e)
                    if (!chosen[e] && w[e] > bv) { bv = w[e]; bi = e; }
                chosen[bi] = 1; ksum += bv;
            }
            const float rinv = 1.f / (ksum + 1e-6f);
            for (int e = 0; e < NE; ++e) wfout[e] = chosen[e] ? w[e] * rinv : 0.f;
        } else {
            for (int e = 0; e < NE; ++e) wfout[e] = w[e];
        }
    }
}

// ---------------------------------------------------------------------------
// K3 v3: rh+combine, ZERO-barrier main loop.
// Old version: 32 K-steps x 2 __syncthreads each, staging latency fully
// exposed per step (vmcnt(0) drain at every barrier) -> ~107 us for 2 GFLOP.
// New: MFMA fragments loaded DIRECTLY from global (A-frag lane layout
// row=lane&15, kslice=(lane>>4)*8 maps to 64B-contiguous reads of Xc / Ab).
// K split 4-ways across waves (each wave: 16 tokens x 64 r x 512 K, 8
// unrolled steps of {10 independent 16B loads + 8 MFMA}, no barriers).
// One end barrier + 4-way LDS reduce, then wfin-scaled bf16 store.
// ---------------------------------------------------------------------------
__global__ __launch_bounds__(256) void rhfused_kernel(
    __hip_bfloat16* Xc, const __hip_bfloat16* __restrict__ Ab,
    const float* __restrict__ wfin)
{
    __shared__ __align__(16) float red[4][16][64];   // 16 KB partials
    __shared__ __align__(16) float wf[16 * 16];      // 1 KB routing weights
    const int tid = threadIdx.x;
    const int wave = tid >> 6, lane = tid & 63;
    const int qm = lane & 15, quad = lane >> 4;
    const int t0 = blockIdx.x * 16;

    // wave's K slice: [wave*512, wave*512+512)
    const __hip_bfloat16* xrow =
        Xc + (size_t)(t0 + qm) * KTOT + wave * 512 + quad * 8;
    const __hip_bfloat16* brow =
        Ab + (size_t)qm * D_IN + wave * 512 + quad * 8;

    f32x4 acc[4] = {};
#pragma unroll
    for (int s = 0; s < 8; ++s) {                 // 8 steps x 64 K, no barriers
        const bf16x8 a0 = *(const bf16x8*)(xrow);
        const bf16x8 a1 = *(const bf16x8*)(xrow + 32);
        bf16x8 b0[4], b1[4];
#pragma unroll
        for (int nf = 0; nf < 4; ++nf) {
            b0[nf] = *(const bf16x8*)(brow + (size_t)nf * 16 * D_IN);
            b1[nf] = *(const bf16x8*)(brow + (size_t)nf * 16 * D_IN + 32);
        }
        xrow += 64; brow += 64;
#pragma unroll
        for (int nf = 0; nf < 4; ++nf) {
            acc[nf] = __builtin_amdgcn_mfma_f32_16x16x32_bf16(a0, b0[nf], acc[nf], 0, 0, 0);
            acc[nf] = __builtin_amdgcn_mfma_f32_16x16x32_bf16(a1, b1[nf], acc[nf], 0, 0, 0);
        }
    }

    // C/D layout: col(n=r-dim)=lane&15, row(m=token)=quad*4+reg
#pragma unroll
    for (int nf = 0; nf < 4; ++nf)
#pragma unroll
        for (int r = 0; r < 4; ++r)
            red[wave][quad * 4 + r][nf * 16 + qm] = acc[nf][r];

    if (tid < 64)
        ((float4*)wf)[tid] = ((const float4*)(wfin + (size_t)t0 * NE))[tid];
    __syncthreads();

#pragma unroll
    for (int it = 0; it < 8; ++it) {
        const int s = it * 256 + tid;      // bf16x8 store index
        const int t = s >> 7;              // 128 chunks per token
        const int chunk = s & 127;
        const int e = chunk >> 3, r0 = (chunk & 7) * 8;
        const float w = wf[t * 16 + e];
        union { bf16x8 v; __hip_bfloat16 h[8]; } u;
#pragma unroll
        for (int q = 0; q < 8; ++q) {
            const float rh = red[0][t][r0 + q] + red[1][t][r0 + q]
                           + red[2][t][r0 + q] + red[3][t][r0 + q];
            u.h[q] = __float2bfloat16(w * rh);
        }
        *(bf16x8*)(Xc + (size_t)(t0 + t) * KTOT + D_IN + chunk * 8) = u.v;
    }
}

// ---------------------------------------------------------------------------
// K4: main GEMM C = Xc @ Wc^T + bias (M=8192, N=2048, K=3072).
// 128x128 tile, XOR-swizzled LDS, bm-fastest grid.
// ---------------------------------------------------------------------------
__global__ __launch_bounds__(256) void gemm_kernel(
    const __hip_bfloat16* __restrict__ Am,
    const __hip_bfloat16* __restrict__ Bm,
    const float* __restrict__ bias,
    float* __restrict__ C, int M, int N)
{
    __shared__ __hip_bfloat16 lds_a[128 * 64];
    __shared__ __hip_bfloat16 lds_b[128 * 64];
    const int tid = threadIdx.x;
    const int wave = tid >> 6, lane = tid & 63;
    const int bm = blockIdx.x, bn = blockIdx.y;    // bm fastest
    const int qm = lane & 15, quad = lane >> 4;
    const int ar = lane >> 3;
    const int ac = ((lane & 7) ^ ar) * 8;          // XOR-swizzled source granule

    f32x4 acc[4][4] = {};
    const int wm = (wave >> 1) * 64, wn = (wave & 1) * 64;

    const __hip_bfloat16* ga[4];
    const __hip_bfloat16* gb[4];
#pragma unroll
    for (int j = 0; j < 4; ++j) {
        ga[j] = Am + (size_t)(bm * 128 + wave * 32 + j * 8 + ar) * KTOT + ac;
        gb[j] = Bm + (size_t)(bn * 128 + wave * 32 + j * 8 + ar) * KTOT + ac;
    }

    for (int k0 = 0; k0 < KTOT; k0 += 64) {
#pragma unroll
        for (int j = 0; j < 4; ++j) {
            async_ld16(ga[j], (void*)&lds_a[(wave * 4 + j) * 512]);
            async_ld16(gb[j], (void*)&lds_b[(wave * 4 + j) * 512]);
            ga[j] += 64; gb[j] += 64;
        }
        __syncthreads();

#pragma unroll
        for (int kk = 0; kk < 64; kk += 32) {
            const int cg = (kk >> 3) + quad;
            const int sw = (cg ^ (qm & 7)) * 8;
            bf16x8 af[4], bfr[4];
#pragma unroll
            for (int i = 0; i < 4; ++i)
                af[i] = *(const bf16x8*)&lds_a[(wm + i * 16 + qm) * 64 + sw];
#pragma unroll
            for (int j = 0; j < 4; ++j)
                bfr[j] = *(const bf16x8*)&lds_b[(wn + j * 16 + qm) * 64 + sw];
#pragma unroll
            for (int i = 0; i < 4; ++i)
#pragma unroll
                for (int j = 0; j < 4; ++j)
                    acc[i][j] = __builtin_amdgcn_mfma_f32_16x16x32_bf16(
                        af[i], bfr[j], acc[i][j], 0, 0, 0);
        }
        __syncthreads();
    }

    const size_t row0 = (size_t)bm * 128 + wm;
    const int col0 = bn * 128 + wn;
#pragma unroll
    for (int j = 0; j < 4; ++j) {
        const int col = col0 + j * 16 + qm;
        const float bb = bias[col];
#pragma unroll
        for (int i = 0; i < 4; ++i) {
#pragma unroll
            for (int r = 0; r < 4; ++r) {
                const size_t row = row0 + i * 16 + quad * 4 + r;
                C[row * (size_t)N + col] = acc[i][j][r] + bb;
            }
        }
    }
}

extern "C" void kernel_launch(void* const* d_in, const int* in_sizes, int n_in,
                              void* d_out, int out_size, void* d_ws, size_t ws_size,
                              hipStream_t stream) {
    const float* x    = (const float*)d_in[0];
    const float* Wb   = (const float*)d_in[1];
    const float* bb   = (const float*)d_in[2];
    const float* A    = (const float*)d_in[3];
    const float* Bm   = (const float*)d_in[4];
    const float* Wr   = (const float*)d_in[5];
    const int*   topk = (const int*)d_in[6];
    float* out = (float*)d_out;
    const int T = in_sizes[0] / D_IN;   // 8192 tokens

    __hip_bfloat16* Xc = (__hip_bfloat16*)d_ws;                                 // T*KTOT bf16 (48MB)
    __hip_bfloat16* Wc = (__hip_bfloat16*)((char*)d_ws + (size_t)T * KTOT * 2); // D_OUT*KTOT bf16 (12MB)
    // Parked in d_out (fully overwritten by the final GEMM):
    __hip_bfloat16* Ab = (__hip_bfloat16*)d_out;              // 256 KB at front
    float* wfin = (float*)d_out + 8 * 1024 * 1024;            // 512 KB at +32MB

    castwa_kernel<<<D_OUT + RNK, 384, 0, stream>>>(Wb, Bm, A, Wc, Ab);
    prep_kernel<<<T / 8, 256, 0, stream>>>(x, Wr, topk, Xc, wfin);
    rhfused_kernel<<<T / 16, 256, 0, stream>>>(Xc, Ab, wfin);
    gemm_kernel<<<dim3(T / 128, D_OUT / 128), 256, 0, stream>>>(Xc, Wc, bb, out, T, D_OUT);
}

// Round 3
// 278.520 us; speedup vs baseline: 1.0976x; 1.0976x over previous
//
#include <hip/hip_runtime.h>
#include <hip/hip_bf16.h>

#define D_IN  2048
#define D_OUT 2048
#define RNK   64
#define NE    16
#define KTOT  3072   // D_IN + NE*RNK

typedef __attribute__((ext_vector_type(8))) short bf16x8;
typedef __attribute__((ext_vector_type(4))) float f32x4;

__device__ __forceinline__ void async_ld16(const void* g, void* l) {
    __builtin_amdgcn_global_load_lds(
        (const __attribute__((address_space(1))) void*)g,
        (__attribute__((address_space(3))) void*)l,
        16, 0, 0);
}

// ---------------------------------------------------------------------------
// K1: merged weight prep.
//  blocks [0,2048):   Wc row n = [ W_base | B' ], B'[n][e*64+r] = B[e][n][r]
//  blocks [2048,2112): Ab row r = bf16(A[r])  (parked in d_out)
// ---------------------------------------------------------------------------
__global__ __launch_bounds__(384) void castwa_kernel(
    const float* __restrict__ Wb, const float* __restrict__ Bm,
    const float* __restrict__ A,
    __hip_bfloat16* __restrict__ Wc, __hip_bfloat16* __restrict__ Ab)
{
    const int c = threadIdx.x * 8;
    const float* src;
    __hip_bfloat16* dst;
    if (blockIdx.x < D_OUT) {
        const int n = blockIdx.x;
        if (c < D_IN) {
            src = Wb + (size_t)n * D_IN + c;
        } else {
            const int j = c - D_IN;
            const int e = j >> 6, r = j & 63;
            src = Bm + ((size_t)e * D_OUT + n) * RNK + r;
        }
        dst = Wc + (size_t)n * KTOT + c;
    } else {
        if (c >= D_IN) return;
        const int r = blockIdx.x - D_OUT;
        src = A + (size_t)r * D_IN + c;
        dst = Ab + (size_t)r * D_IN + c;
    }
    const float4 a = *(const float4*)src;
    const float4 b = *(const float4*)(src + 4);
    const float vv[8] = {a.x, a.y, a.z, a.w, b.x, b.y, b.z, b.w};
    union { bf16x8 v; __hip_bfloat16 h[8]; } u;
#pragma unroll
    for (int q = 0; q < 8; ++q) u.h[q] = __float2bfloat16(vv[q]);
    *(bf16x8*)dst = u.v;
}

// ---------------------------------------------------------------------------
// K2 (fused prep+rh): per block = 16 tokens, 512 threads (8 waves), grid 512.
// Phase 1: Wr LDS-staged fp32 router (verified logic) + bf16(x) emitted to
//   BOTH global Xc and an LDS-resident swizzled xb[16][2048] tile.
// Phase 2: RH = xb @ Ab^T via MFMA, K split 8-ways across waves, A-frags
//   from LDS xb (XOR-swizzled), B-frags direct from L2-hot Ab; no barriers.
// Then 8-way LDS reduce (red overlays xb) + softmax/top-k weights (wf
//   overlays the Wr stage) and the verified t[e*64+r]=wf[e]*rh[r] store.
// LDS = 64KB xb + 16KB stage = 80KB exactly -> 2 blocks/CU, 16 waves/CU.
// ---------------------------------------------------------------------------
__global__ __launch_bounds__(512) void prep2_kernel(
    const float* __restrict__ x, const float* __restrict__ Wr,
    const __hip_bfloat16* __restrict__ Ab,
    const int* __restrict__ topk_p, __hip_bfloat16* __restrict__ Xc)
{
    __shared__ __align__(16) char smem[81920];
    __hip_bfloat16* xb = (__hip_bfloat16*)smem;      // [16][2048] bf16, swizzled
    float* stage = (float*)(smem + 65536);           // 16KB: Wr chunk staging
    float* red = (float*)smem;                       // overlay: [8][16][64] f32
    float* wf  = (float*)(smem + 65536);             // overlay: [16][16] f32

    const int tid = threadIdx.x;
    const int wave = tid >> 6, lane = tid & 63;
    const int qm = lane & 15, quad = lane >> 4;
    const int t0 = blockIdx.x * 16;
    const int tA = t0 + wave * 2;                    // wave owns 2 tokens

    float acc[NE][2];
#pragma unroll
    for (int e = 0; e < NE; ++e) { acc[e][0] = 0.f; acc[e][1] = 0.f; }

    const float4* x4 = (const float4*)x;
    float4 xv[2], xn[2];
    xv[0] = x4[(size_t)tA * 512 + lane];
    xv[1] = x4[(size_t)(tA + 1) * 512 + lane];

    // ---- phase 1: 8 K-chunks of 256 floats ----
    for (int c = 0; c < 8; ++c) {
        // stage Wr chunk c (16 rows x 256 f32 = 16KB); wave stages rows w, w+8
        async_ld16(Wr + (size_t)wave * D_IN + c * 256 + lane * 4,
                   (void*)(stage + wave * 256));
        async_ld16(Wr + (size_t)(wave + 8) * D_IN + c * 256 + lane * 4,
                   (void*)(stage + (wave + 8) * 256));
        if (c < 7) {   // prefetch next x chunk; its latency drains at the barrier
            xn[0] = x4[(size_t)tA * 512 + (c + 1) * 64 + lane];
            xn[1] = x4[(size_t)(tA + 1) * 512 + (c + 1) * 64 + lane];
        }
        __syncthreads();   // drain Wr stage (x prefetch rides the same wait)

#pragma unroll
        for (int t = 0; t < 2; ++t) {
            const int tl = wave * 2 + t;
            union { short4 v; __hip_bfloat16 h[4]; } u;
            u.h[0] = __float2bfloat16(xv[t].x); u.h[1] = __float2bfloat16(xv[t].y);
            u.h[2] = __float2bfloat16(xv[t].z); u.h[3] = __float2bfloat16(xv[t].w);
            *(short4*)(Xc + (size_t)(t0 + tl) * KTOT + c * 256 + lane * 4) = u.v;
            // swizzled LDS write: granule gg -> gg ^ (row&7)
            const int gg = c * 32 + (lane >> 1);
            const int pg = gg ^ (tl & 7);
            *(short4*)((char*)xb + tl * 4096 + pg * 16 + (lane & 1) * 8) = u.v;
        }
        const float4* wr4 = (const float4*)stage;
#pragma unroll
        for (int e = 0; e < NE; ++e) {
            const float4 wv = wr4[e * 64 + lane];
            acc[e][0] += xv[0].x*wv.x + xv[0].y*wv.y + xv[0].z*wv.z + xv[0].w*wv.w;
            acc[e][1] += xv[1].x*wv.x + xv[1].y*wv.y + xv[1].z*wv.z + xv[1].w*wv.w;
        }
        __syncthreads();   // all waves done with stage before next overwrite
        if (c < 7) { xv[0] = xn[0]; xv[1] = xn[1]; }
    }

    // ---- router reduce + softmax/top-k -> wf (LDS, overlays stage) ----
#pragma unroll
    for (int off = 32; off; off >>= 1)
#pragma unroll
        for (int e = 0; e < NE; ++e) {
            acc[e][0] += __shfl_xor(acc[e][0], off, 64);
            acc[e][1] += __shfl_xor(acc[e][1], off, 64);
        }
    if (lane < 2) {
        const int tt = lane;
        const int k = topk_p[0];
        float m = -1e30f;
#pragma unroll
        for (int e = 0; e < NE; ++e) m = fmaxf(m, acc[e][tt]);
        float w[NE]; float ssum = 0.f;
#pragma unroll
        for (int e = 0; e < NE; ++e) { w[e] = __expf(acc[e][tt] - m); ssum += w[e]; }
        const float inv = 1.f / ssum;
#pragma unroll
        for (int e = 0; e < NE; ++e) w[e] *= inv;
        float* wfout = wf + (size_t)(wave * 2 + tt) * NE;
        if (k > 0 && k < NE) {
            int chosen[NE];
#pragma unroll
            for (int e = 0; e < NE; ++e) chosen[e] = 0;
            float ksum = 0.f;
            for (int it = 0; it < k; ++it) {
                int bi = 0; float bv = -1.f;
                for (int e = 0; e < NE; ++e)
                    if (!chosen[e] && w[e] > bv) { bv = w[e]; bi = e; }
                chosen[bi] = 1; ksum += bv;
            }
            const float rinv = 1.f / (ksum + 1e-6f);
            for (int e = 0; e < NE; ++e) wfout[e] = chosen[e] ? w[e] * rinv : 0.f;
        } else {
            for (int e = 0; e < NE; ++e) wfout[e] = w[e];
        }
    }

    // ---- phase 2: RH MFMA; wave w covers K slice [w*256, w*256+256) ----
    f32x4 racc[4] = {};
    const int kb = wave * 256;
#pragma unroll
    for (int s = 0; s < 4; ++s) {
        const int k0 = kb + s * 64;
        const int gg0 = (k0 >> 3) + quad;
        const bf16x8 a0 = *(const bf16x8*)((char*)xb + qm * 4096 + ((gg0 ^ (qm & 7)) * 16));
        const bf16x8 a1 = *(const bf16x8*)((char*)xb + qm * 4096 + (((gg0 + 4) ^ (qm & 7)) * 16));
        bf16x8 b0[4], b1[4];
#pragma unroll
        for (int nf = 0; nf < 4; ++nf) {
            const __hip_bfloat16* bp = Ab + (size_t)(qm + nf * 16) * D_IN + k0 + quad * 8;
            b0[nf] = *(const bf16x8*)bp;
            b1[nf] = *(const bf16x8*)(bp + 32);
        }
#pragma unroll
        for (int nf = 0; nf < 4; ++nf) {
            racc[nf] = __builtin_amdgcn_mfma_f32_16x16x32_bf16(a0, b0[nf], racc[nf], 0, 0, 0);
            racc[nf] = __builtin_amdgcn_mfma_f32_16x16x32_bf16(a1, b1[nf], racc[nf], 0, 0, 0);
        }
    }
    __syncthreads();   // all xb reads done -> safe to overlay red on xb

    // C/D layout: col(r-dim)=lane&15, row(token)=quad*4+reg
#pragma unroll
    for (int nf = 0; nf < 4; ++nf)
#pragma unroll
        for (int r = 0; r < 4; ++r)
            red[(wave * 16 + quad * 4 + r) * 64 + nf * 16 + qm] = racc[nf][r];
    __syncthreads();

    // ---- epilogue: t[e*64+r] = wf[e] * rh[r], coalesced bf16x8 stores ----
#pragma unroll
    for (int it = 0; it < 4; ++it) {
        const int s = it * 512 + tid;      // bf16x8 store index (2048 total)
        const int t = s >> 7;              // 128 chunks per token
        const int chunk = s & 127;
        const int e = chunk >> 3, r0 = (chunk & 7) * 8;
        const float wgt = wf[t * 16 + e];
        float4 s0 = {0.f, 0.f, 0.f, 0.f}, s1 = {0.f, 0.f, 0.f, 0.f};
#pragma unroll
        for (int w2 = 0; w2 < 8; ++w2) {
            const float4 p0 = ((const float4*)red)[(w2 * 16 + t) * 16 + (r0 >> 2)];
            const float4 p1 = ((const float4*)red)[(w2 * 16 + t) * 16 + (r0 >> 2) + 1];
            s0.x += p0.x; s0.y += p0.y; s0.z += p0.z; s0.w += p0.w;
            s1.x += p1.x; s1.y += p1.y; s1.z += p1.z; s1.w += p1.w;
        }
        union { bf16x8 v; __hip_bfloat16 h[8]; } u;
        u.h[0] = __float2bfloat16(wgt * s0.x); u.h[1] = __float2bfloat16(wgt * s0.y);
        u.h[2] = __float2bfloat16(wgt * s0.z); u.h[3] = __float2bfloat16(wgt * s0.w);
        u.h[4] = __float2bfloat16(wgt * s1.x); u.h[5] = __float2bfloat16(wgt * s1.y);
        u.h[6] = __float2bfloat16(wgt * s1.z); u.h[7] = __float2bfloat16(wgt * s1.w);
        *(bf16x8*)(Xc + (size_t)(t0 + t) * KTOT + D_IN + chunk * 8) = u.v;
    }
}

// ---------------------------------------------------------------------------
// K4: main GEMM C = Xc @ Wc^T + bias (M=8192, N=2048, K=3072).
// 128x128 tile, XOR-swizzled LDS, bm-fastest grid.
// ---------------------------------------------------------------------------
__global__ __launch_bounds__(256) void gemm_kernel(
    const __hip_bfloat16* __restrict__ Am,
    const __hip_bfloat16* __restrict__ Bm,
    const float* __restrict__ bias,
    float* __restrict__ C, int M, int N)
{
    __shared__ __hip_bfloat16 lds_a[128 * 64];
    __shared__ __hip_bfloat16 lds_b[128 * 64];
    const int tid = threadIdx.x;
    const int wave = tid >> 6, lane = tid & 63;
    const int bm = blockIdx.x, bn = blockIdx.y;    // bm fastest
    const int qm = lane & 15, quad = lane >> 4;
    const int ar = lane >> 3;
    const int ac = ((lane & 7) ^ ar) * 8;          // XOR-swizzled source granule

    f32x4 acc[4][4] = {};
    const int wm = (wave >> 1) * 64, wn = (wave & 1) * 64;

    const __hip_bfloat16* ga[4];
    const __hip_bfloat16* gb[4];
#pragma unroll
    for (int j = 0; j < 4; ++j) {
        ga[j] = Am + (size_t)(bm * 128 + wave * 32 + j * 8 + ar) * KTOT + ac;
        gb[j] = Bm + (size_t)(bn * 128 + wave * 32 + j * 8 + ar) * KTOT + ac;
    }

    for (int k0 = 0; k0 < KTOT; k0 += 64) {
#pragma unroll
        for (int j = 0; j < 4; ++j) {
            async_ld16(ga[j], (void*)&lds_a[(wave * 4 + j) * 512]);
            async_ld16(gb[j], (void*)&lds_b[(wave * 4 + j) * 512]);
            ga[j] += 64; gb[j] += 64;
        }
        __syncthreads();

#pragma unroll
        for (int kk = 0; kk < 64; kk += 32) {
            const int cg = (kk >> 3) + quad;
            const int sw = (cg ^ (qm & 7)) * 8;
            bf16x8 af[4], bfr[4];
#pragma unroll
            for (int i = 0; i < 4; ++i)
                af[i] = *(const bf16x8*)&lds_a[(wm + i * 16 + qm) * 64 + sw];
#pragma unroll
            for (int j = 0; j < 4; ++j)
                bfr[j] = *(const bf16x8*)&lds_b[(wn + j * 16 + qm) * 64 + sw];
#pragma unroll
            for (int i = 0; i < 4; ++i)
#pragma unroll
                for (int j = 0; j < 4; ++j)
                    acc[i][j] = __builtin_amdgcn_mfma_f32_16x16x32_bf16(
                        af[i], bfr[j], acc[i][j], 0, 0, 0);
        }
        __syncthreads();
    }

    const size_t row0 = (size_t)bm * 128 + wm;
    const int col0 = bn * 128 + wn;
#pragma unroll
    for (int j = 0; j < 4; ++j) {
        const int col = col0 + j * 16 + qm;
        const float bb = bias[col];
#pragma unroll
        for (int i = 0; i < 4; ++i) {
#pragma unroll
            for (int r = 0; r < 4; ++r) {
                const size_t row = row0 + i * 16 + quad * 4 + r;
                C[row * (size_t)N + col] = acc[i][j][r] + bb;
            }
        }
    }
}

extern "C" void kernel_launch(void* const* d_in, const int* in_sizes, int n_in,
                              void* d_out, int out_size, void* d_ws, size_t ws_size,
                              hipStream_t stream) {
    const float* x    = (const float*)d_in[0];
    const float* Wb   = (const float*)d_in[1];
    const float* bb   = (const float*)d_in[2];
    const float* A    = (const float*)d_in[3];
    const float* Bm   = (const float*)d_in[4];
    const float* Wr   = (const float*)d_in[5];
    const int*   topk = (const int*)d_in[6];
    float* out = (float*)d_out;
    const int T = in_sizes[0] / D_IN;   // 8192 tokens

    __hip_bfloat16* Xc = (__hip_bfloat16*)d_ws;                                 // T*KTOT bf16 (48MB)
    __hip_bfloat16* Wc = (__hip_bfloat16*)((char*)d_ws + (size_t)T * KTOT * 2); // D_OUT*KTOT bf16 (12MB)
    // Parked in d_out (fully overwritten by the final GEMM):
    __hip_bfloat16* Ab = (__hip_bfloat16*)d_out;              // 256 KB at front

    castwa_kernel<<<D_OUT + RNK, 384, 0, stream>>>(Wb, Bm, A, Wc, Ab);
    prep2_kernel<<<T / 16, 512, 0, stream>>>(x, Wr, Ab, topk, Xc);
    gemm_kernel<<<dim3(T / 128, D_OUT / 128), 256, 0, stream>>>(Xc, Wc, bb, out, T, D_OUT);
}

// Round 4
// 277.745 us; speedup vs baseline: 1.1007x; 1.0028x over previous
//
#include <hip/hip_runtime.h>
#include <hip/hip_bf16.h>

#define D_IN  2048
#define D_OUT 2048
#define RNK   64
#define NE    16
#define KTOT  3072   // D_IN + NE*RNK
#define NTILE 48     // KTOT / 64

typedef __attribute__((ext_vector_type(8))) short bf16x8;
typedef __attribute__((ext_vector_type(4))) float f32x4;

__device__ __forceinline__ void async_ld16(const void* g, void* l) {
    __builtin_amdgcn_global_load_lds(
        (const __attribute__((address_space(1))) void*)g,
        (__attribute__((address_space(3))) void*)l,
        16, 0, 0);
}

// ---------------------------------------------------------------------------
// K1: merged weight prep.
//  blocks [0,2048):   Wc row n = [ W_base | B' ], B'[n][e*64+r] = B[e][n][r]
//  blocks [2048,2112): Ab row r = bf16(A[r])  (parked in d_out)
// ---------------------------------------------------------------------------
__global__ __launch_bounds__(384) void castwa_kernel(
    const float* __restrict__ Wb, const float* __restrict__ Bm,
    const float* __restrict__ A,
    __hip_bfloat16* __restrict__ Wc, __hip_bfloat16* __restrict__ Ab)
{
    const int c = threadIdx.x * 8;
    const float* src;
    __hip_bfloat16* dst;
    if (blockIdx.x < D_OUT) {
        const int n = blockIdx.x;
        if (c < D_IN) {
            src = Wb + (size_t)n * D_IN + c;
        } else {
            const int j = c - D_IN;
            const int e = j >> 6, r = j & 63;
            src = Bm + ((size_t)e * D_OUT + n) * RNK + r;
        }
        dst = Wc + (size_t)n * KTOT + c;
    } else {
        if (c >= D_IN) return;
        const int r = blockIdx.x - D_OUT;
        src = A + (size_t)r * D_IN + c;
        dst = Ab + (size_t)r * D_IN + c;
    }
    const float4 a = *(const float4*)src;
    const float4 b = *(const float4*)(src + 4);
    const float vv[8] = {a.x, a.y, a.z, a.w, b.x, b.y, b.z, b.w};
    union { bf16x8 v; __hip_bfloat16 h[8]; } u;
#pragma unroll
    for (int q = 0; q < 8; ++q) u.h[q] = __float2bfloat16(vv[q]);
    *(bf16x8*)dst = u.v;
}

// ---------------------------------------------------------------------------
// K2 (fused prep+rh): per block = 16 tokens, 512 threads (8 waves), grid 512.
// Phase 1: Wr LDS-staged fp32 router + bf16(x) -> global Xc + LDS xb tile.
// Phase 2: RH = xb @ Ab^T via MFMA (K split 8-ways, no barriers), reduce,
// then t[e*64+r] = wfin[e]*rh[r] store. LDS 80KB -> 2 blocks/CU.
// ---------------------------------------------------------------------------
__global__ __launch_bounds__(512) void prep2_kernel(
    const float* __restrict__ x, const float* __restrict__ Wr,
    const __hip_bfloat16* __restrict__ Ab,
    const int* __restrict__ topk_p, __hip_bfloat16* __restrict__ Xc)
{
    __shared__ __align__(16) char smem[81920];
    __hip_bfloat16* xb = (__hip_bfloat16*)smem;      // [16][2048] bf16, swizzled
    float* stage = (float*)(smem + 65536);           // 16KB: Wr chunk staging
    float* red = (float*)smem;                       // overlay: [8][16][64] f32
    float* wf  = (float*)(smem + 65536);             // overlay: [16][16] f32

    const int tid = threadIdx.x;
    const int wave = tid >> 6, lane = tid & 63;
    const int qm = lane & 15, quad = lane >> 4;
    const int t0 = blockIdx.x * 16;
    const int tA = t0 + wave * 2;                    // wave owns 2 tokens

    float acc[NE][2];
#pragma unroll
    for (int e = 0; e < NE; ++e) { acc[e][0] = 0.f; acc[e][1] = 0.f; }

    const float4* x4 = (const float4*)x;
    float4 xv[2], xn[2];
    xv[0] = x4[(size_t)tA * 512 + lane];
    xv[1] = x4[(size_t)(tA + 1) * 512 + lane];

    // ---- phase 1: 8 K-chunks of 256 floats ----
    for (int c = 0; c < 8; ++c) {
        async_ld16(Wr + (size_t)wave * D_IN + c * 256 + lane * 4,
                   (void*)(stage + wave * 256));
        async_ld16(Wr + (size_t)(wave + 8) * D_IN + c * 256 + lane * 4,
                   (void*)(stage + (wave + 8) * 256));
        if (c < 7) {
            xn[0] = x4[(size_t)tA * 512 + (c + 1) * 64 + lane];
            xn[1] = x4[(size_t)(tA + 1) * 512 + (c + 1) * 64 + lane];
        }
        __syncthreads();

#pragma unroll
        for (int t = 0; t < 2; ++t) {
            const int tl = wave * 2 + t;
            union { short4 v; __hip_bfloat16 h[4]; } u;
            u.h[0] = __float2bfloat16(xv[t].x); u.h[1] = __float2bfloat16(xv[t].y);
            u.h[2] = __float2bfloat16(xv[t].z); u.h[3] = __float2bfloat16(xv[t].w);
            *(short4*)(Xc + (size_t)(t0 + tl) * KTOT + c * 256 + lane * 4) = u.v;
            const int gg = c * 32 + (lane >> 1);
            const int pg = gg ^ (tl & 7);
            *(short4*)((char*)xb + tl * 4096 + pg * 16 + (lane & 1) * 8) = u.v;
        }
        const float4* wr4 = (const float4*)stage;
#pragma unroll
        for (int e = 0; e < NE; ++e) {
            const float4 wv = wr4[e * 64 + lane];
            acc[e][0] += xv[0].x*wv.x + xv[0].y*wv.y + xv[0].z*wv.z + xv[0].w*wv.w;
            acc[e][1] += xv[1].x*wv.x + xv[1].y*wv.y + xv[1].z*wv.z + xv[1].w*wv.w;
        }
        __syncthreads();
        if (c < 7) { xv[0] = xn[0]; xv[1] = xn[1]; }
    }

    // ---- router reduce + softmax/top-k -> wf ----
#pragma unroll
    for (int off = 32; off; off >>= 1)
#pragma unroll
        for (int e = 0; e < NE; ++e) {
            acc[e][0] += __shfl_xor(acc[e][0], off, 64);
            acc[e][1] += __shfl_xor(acc[e][1], off, 64);
        }
    if (lane < 2) {
        const int tt = lane;
        const int k = topk_p[0];
        float m = -1e30f;
#pragma unroll
        for (int e = 0; e < NE; ++e) m = fmaxf(m, acc[e][tt]);
        float w[NE]; float ssum = 0.f;
#pragma unroll
        for (int e = 0; e < NE; ++e) { w[e] = __expf(acc[e][tt] - m); ssum += w[e]; }
        const float inv = 1.f / ssum;
#pragma unroll
        for (int e = 0; e < NE; ++e) w[e] *= inv;
        float* wfout = wf + (size_t)(wave * 2 + tt) * NE;
        if (k > 0 && k < NE) {
            int chosen[NE];
#pragma unroll
            for (int e = 0; e < NE; ++e) chosen[e] = 0;
            float ksum = 0.f;
            for (int it = 0; it < k; ++it) {
                int bi = 0; float bv = -1.f;
                for (int e = 0; e < NE; ++e)
                    if (!chosen[e] && w[e] > bv) { bv = w[e]; bi = e; }
                chosen[bi] = 1; ksum += bv;
            }
            const float rinv = 1.f / (ksum + 1e-6f);
            for (int e = 0; e < NE; ++e) wfout[e] = chosen[e] ? w[e] * rinv : 0.f;
        } else {
            for (int e = 0; e < NE; ++e) wfout[e] = w[e];
        }
    }

    // ---- phase 2: RH MFMA; wave w covers K slice [w*256, w*256+256) ----
    f32x4 racc[4] = {};
    const int kb = wave * 256;
#pragma unroll
    for (int s = 0; s < 4; ++s) {
        const int k0 = kb + s * 64;
        const int gg0 = (k0 >> 3) + quad;
        const bf16x8 a0 = *(const bf16x8*)((char*)xb + qm * 4096 + ((gg0 ^ (qm & 7)) * 16));
        const bf16x8 a1 = *(const bf16x8*)((char*)xb + qm * 4096 + (((gg0 + 4) ^ (qm & 7)) * 16));
        bf16x8 b0[4], b1[4];
#pragma unroll
        for (int nf = 0; nf < 4; ++nf) {
            const __hip_bfloat16* bp = Ab + (size_t)(qm + nf * 16) * D_IN + k0 + quad * 8;
            b0[nf] = *(const bf16x8*)bp;
            b1[nf] = *(const bf16x8*)(bp + 32);
        }
#pragma unroll
        for (int nf = 0; nf < 4; ++nf) {
            racc[nf] = __builtin_amdgcn_mfma_f32_16x16x32_bf16(a0, b0[nf], racc[nf], 0, 0, 0);
            racc[nf] = __builtin_amdgcn_mfma_f32_16x16x32_bf16(a1, b1[nf], racc[nf], 0, 0, 0);
        }
    }
    __syncthreads();

#pragma unroll
    for (int nf = 0; nf < 4; ++nf)
#pragma unroll
        for (int r = 0; r < 4; ++r)
            red[(wave * 16 + quad * 4 + r) * 64 + nf * 16 + qm] = racc[nf][r];
    __syncthreads();

#pragma unroll
    for (int it = 0; it < 4; ++it) {
        const int s = it * 512 + tid;
        const int t = s >> 7;
        const int chunk = s & 127;
        const int e = chunk >> 3, r0 = (chunk & 7) * 8;
        const float wgt = wf[t * 16 + e];
        float4 s0 = {0.f, 0.f, 0.f, 0.f}, s1 = {0.f, 0.f, 0.f, 0.f};
#pragma unroll
        for (int w2 = 0; w2 < 8; ++w2) {
            const float4 p0 = ((const float4*)red)[(w2 * 16 + t) * 16 + (r0 >> 2)];
            const float4 p1 = ((const float4*)red)[(w2 * 16 + t) * 16 + (r0 >> 2) + 1];
            s0.x += p0.x; s0.y += p0.y; s0.z += p0.z; s0.w += p0.w;
            s1.x += p1.x; s1.y += p1.y; s1.z += p1.z; s1.w += p1.w;
        }
        union { bf16x8 v; __hip_bfloat16 h[8]; } u;
        u.h[0] = __float2bfloat16(wgt * s0.x); u.h[1] = __float2bfloat16(wgt * s0.y);
        u.h[2] = __float2bfloat16(wgt * s0.z); u.h[3] = __float2bfloat16(wgt * s0.w);
        u.h[4] = __float2bfloat16(wgt * s1.x); u.h[5] = __float2bfloat16(wgt * s1.y);
        u.h[6] = __float2bfloat16(wgt * s1.z); u.h[7] = __float2bfloat16(wgt * s1.w);
        *(bf16x8*)(Xc + (size_t)(t0 + t) * KTOT + D_IN + chunk * 8) = u.v;
    }
}

// ---------------------------------------------------------------------------
// K4 v2: 256x256 8-phase GEMM (T2+T3+T4+T5). 512 thr / 8 waves (2M x 4N),
// BK=64, 128KB LDS double-buffer. Wave owns split rows {wm2*64+[0,64),
// 128+wm2*64+[0,64)} so phase quadrant (mh,nh) maps to contiguous LDS
// halves. Per tile: 4 phases {ds_read quadrant frags -> staging issue ->
// counted vmcnt -> raw s_barrier -> setprio(1) 16 MFMA setprio(0) ->
// s_barrier}. Staging: next tile's (A,B) h0-pair at ph1, h1-pair at ph2;
// vmcnt(4) only at ph1/ph4 (loads stay in flight across barriers -> no
// vmcnt(0) drain = the m97 ~900TF wall). XOR-granule swizzle via
// pre-swizzled global source + swizzled ds_read (both-sides, rule 21).
// ---------------------------------------------------------------------------
#define LDA(BO, MH, i, kk) (*(const bf16x8*)(ldsc + (BO) + \
    ((MH) * 128 + wm2 * 64 + (i) * 16 + qm) * 128 + \
    ((((kk) * 4 + quad) ^ (qm & 7)) * 16)))
#define LDB(BO, NH, j, kk) (*(const bf16x8*)(ldsc + 65536 + (BO) + \
    ((NH) * 128 + wn4 * 32 + (j) * 16 + qm) * 128 + \
    ((((kk) * 4 + quad) ^ (qm & 7)) * 16)))

#define PHASE(BO, MH, NH, STAGE_STMT, WAIT_STMT) do { \
    bf16x8 af0[4], bv0[2], af1[4], bv1[2]; \
    _Pragma("unroll") for (int i = 0; i < 4; ++i) af0[i] = LDA(BO, MH, i, 0); \
    _Pragma("unroll") for (int j = 0; j < 2; ++j) bv0[j] = LDB(BO, NH, j, 0); \
    STAGE_STMT; \
    WAIT_STMT; \
    __builtin_amdgcn_sched_barrier(0); \
    __builtin_amdgcn_s_barrier(); \
    __builtin_amdgcn_sched_barrier(0); \
    __builtin_amdgcn_s_setprio(1); \
    _Pragma("unroll") for (int i = 0; i < 4; ++i) \
    _Pragma("unroll") for (int j = 0; j < 2; ++j) \
        acc[(MH)*4+i][(NH)*2+j] = __builtin_amdgcn_mfma_f32_16x16x32_bf16( \
            af0[i], bv0[j], acc[(MH)*4+i][(NH)*2+j], 0, 0, 0); \
    _Pragma("unroll") for (int i = 0; i < 4; ++i) af1[i] = LDA(BO, MH, i, 1); \
    _Pragma("unroll") for (int j = 0; j < 2; ++j) bv1[j] = LDB(BO, NH, j, 1); \
    _Pragma("unroll") for (int i = 0; i < 4; ++i) \
    _Pragma("unroll") for (int j = 0; j < 2; ++j) \
        acc[(MH)*4+i][(NH)*2+j] = __builtin_amdgcn_mfma_f32_16x16x32_bf16( \
            af1[i], bv1[j], acc[(MH)*4+i][(NH)*2+j], 0, 0, 0); \
    __builtin_amdgcn_s_setprio(0); \
    __builtin_amdgcn_sched_barrier(0); \
    __builtin_amdgcn_s_barrier(); \
    __builtin_amdgcn_sched_barrier(0); \
} while (0)

__global__ __launch_bounds__(512, 2) void gemm2_kernel(
    const __hip_bfloat16* __restrict__ Am,
    const __hip_bfloat16* __restrict__ Bm,
    const float* __restrict__ bias,
    float* __restrict__ C)
{
    __shared__ __align__(16) char smem[131072];   // A:[2][256][64] B:+64KB
    char* ldsc = smem;
    const int tid = threadIdx.x;
    const int w = tid >> 6, lane = tid & 63;
    const int qm = lane & 15, quad = lane >> 4;
    const int wm2 = w >> 2, wn4 = w & 3;

    // XCD swizzle: 256 blocks, XCD x owns bn panel x (1.5MB Wc slice in L2)
    int flat = blockIdx.y * gridDim.x + blockIdx.x;
    flat = (flat & 7) * 32 + (flat >> 3);
    const int bm = flat & 31, bn = flat >> 5;

    // staging source (pre-swizzled: granule g_src = g ^ (row&7))
    const int rb0 = w * 16 + (lane >> 3);
    const int rb1 = rb0 + 8;
    const int gs0 = (lane & 7) ^ (rb0 & 7);
    const int gs1 = (lane & 7) ^ (rb1 & 7);
    const __hip_bfloat16* pA0 = Am + (size_t)(bm * 256 + rb0) * KTOT + gs0 * 8;
    const __hip_bfloat16* pA1 = Am + (size_t)(bm * 256 + rb1) * KTOT + gs1 * 8;
    const __hip_bfloat16* pB0 = Bm + (size_t)(bn * 256 + rb0) * KTOT + gs0 * 8;
    const __hip_bfloat16* pB1 = Bm + (size_t)(bn * 256 + rb1) * KTOT + gs1 * 8;

    f32x4 acc[8][4] = {};

    auto stage_pair = [&](int tn, int hh) {
        const size_t ko = (size_t)tn * 64;
        const size_t ho = (size_t)hh * (128 * KTOT);
        char* da = ldsc + (tn & 1) * 32768 + hh * 16384 + w * 2048;
        async_ld16(pA0 + ho + ko, da);
        async_ld16(pA1 + ho + ko, da + 1024);
        char* db = ldsc + 65536 + (tn & 1) * 32768 + hh * 16384 + w * 2048;
        async_ld16(pB0 + ho + ko, db);
        async_ld16(pB1 + ho + ko, db + 1024);
    };

    // prologue: tile 0 fully staged
    stage_pair(0, 0); stage_pair(0, 1);
    asm volatile("s_waitcnt vmcnt(0)" ::: "memory");
    __builtin_amdgcn_s_barrier();

    for (int t = 0; t < NTILE - 1; ++t) {
        const int bo = (t & 1) * 32768;
        PHASE(bo, 0, 0, stage_pair(t + 1, 0),
              asm volatile("s_waitcnt vmcnt(4)" ::: "memory"));
        PHASE(bo, 1, 0, stage_pair(t + 1, 1), );
        PHASE(bo, 0, 1, , );
        PHASE(bo, 1, 1, ,
              asm volatile("s_waitcnt vmcnt(4)" ::: "memory"));
    }
    {   // tail tile 47 (buf 1), no staging
        const int bo = 32768;
        PHASE(bo, 0, 0, , asm volatile("s_waitcnt vmcnt(0)" ::: "memory"));
        PHASE(bo, 1, 0, , );
        PHASE(bo, 0, 1, , );
        PHASE(bo, 1, 1, , );
    }

    // epilogue: C = acc + bias
    const size_t row0 = (size_t)bm * 256;
    const int col0 = bn * 256;
#pragma unroll
    for (int nh = 0; nh < 2; ++nh)
#pragma unroll
    for (int j = 0; j < 2; ++j) {
        const int col = col0 + nh * 128 + wn4 * 32 + j * 16 + qm;
        const float bb = bias[col];
#pragma unroll
        for (int mh = 0; mh < 2; ++mh)
#pragma unroll
        for (int i = 0; i < 4; ++i) {
#pragma unroll
            for (int r = 0; r < 4; ++r) {
                const size_t row = row0 + mh * 128 + wm2 * 64 + i * 16 + quad * 4 + r;
                C[row * D_OUT + col] = acc[mh * 4 + i][nh * 2 + j][r] + bb;
            }
        }
    }
}

extern "C" void kernel_launch(void* const* d_in, const int* in_sizes, int n_in,
                              void* d_out, int out_size, void* d_ws, size_t ws_size,
                              hipStream_t stream) {
    const float* x    = (const float*)d_in[0];
    const float* Wb   = (const float*)d_in[1];
    const float* bb   = (const float*)d_in[2];
    const float* A    = (const float*)d_in[3];
    const float* Bm   = (const float*)d_in[4];
    const float* Wr   = (const float*)d_in[5];
    const int*   topk = (const int*)d_in[6];
    float* out = (float*)d_out;
    const int T = in_sizes[0] / D_IN;   // 8192 tokens

    __hip_bfloat16* Xc = (__hip_bfloat16*)d_ws;                                 // T*KTOT bf16 (48MB)
    __hip_bfloat16* Wc = (__hip_bfloat16*)((char*)d_ws + (size_t)T * KTOT * 2); // D_OUT*KTOT bf16 (12MB)
    // Parked in d_out (fully overwritten by the final GEMM):
    __hip_bfloat16* Ab = (__hip_bfloat16*)d_out;              // 256 KB at front

    castwa_kernel<<<D_OUT + RNK, 384, 0, stream>>>(Wb, Bm, A, Wc, Ab);
    prep2_kernel<<<T / 16, 512, 0, stream>>>(x, Wr, Ab, topk, Xc);
    gemm2_kernel<<<dim3(32, 8), 512, 0, stream>>>(Xc, Wc, bb, out);
}

// Round 5
// 265.492 us; speedup vs baseline: 1.1515x; 1.0462x over previous
//
#include <hip/hip_runtime.h>
#include <hip/hip_bf16.h>

#define D_IN  2048
#define D_OUT 2048
#define RNK   64
#define NE    16
#define KTOT  3072   // D_IN + NE*RNK
#define NTILE 48     // KTOT / 64

typedef __attribute__((ext_vector_type(8))) short bf16x8;
typedef __attribute__((ext_vector_type(4))) float f32x4;
typedef __attribute__((ext_vector_type(16))) float f32x16;

__device__ __forceinline__ void async_ld16(const void* g, void* l) {
    __builtin_amdgcn_global_load_lds(
        (const __attribute__((address_space(1))) void*)g,
        (__attribute__((address_space(3))) void*)l,
        16, 0, 0);
}

// ---------------------------------------------------------------------------
// K1: merged weight prep.
//  blocks [0,2048):   Wc row n = [ W_base | B' ], B'[n][e*64+r] = B[e][n][r]
//  blocks [2048,2112): Ab row r = bf16(A[r])  (parked in d_out)
// ---------------------------------------------------------------------------
__global__ __launch_bounds__(384) void castwa_kernel(
    const float* __restrict__ Wb, const float* __restrict__ Bm,
    const float* __restrict__ A,
    __hip_bfloat16* __restrict__ Wc, __hip_bfloat16* __restrict__ Ab)
{
    const int c = threadIdx.x * 8;
    const float* src;
    __hip_bfloat16* dst;
    if (blockIdx.x < D_OUT) {
        const int n = blockIdx.x;
        if (c < D_IN) {
            src = Wb + (size_t)n * D_IN + c;
        } else {
            const int j = c - D_IN;
            const int e = j >> 6, r = j & 63;
            src = Bm + ((size_t)e * D_OUT + n) * RNK + r;
        }
        dst = Wc + (size_t)n * KTOT + c;
    } else {
        if (c >= D_IN) return;
        const int r = blockIdx.x - D_OUT;
        src = A + (size_t)r * D_IN + c;
        dst = Ab + (size_t)r * D_IN + c;
    }
    const float4 a = *(const float4*)src;
    const float4 b = *(const float4*)(src + 4);
    const float vv[8] = {a.x, a.y, a.z, a.w, b.x, b.y, b.z, b.w};
    union { bf16x8 v; __hip_bfloat16 h[8]; } u;
#pragma unroll
    for (int q = 0; q < 8; ++q) u.h[q] = __float2bfloat16(vv[q]);
    *(bf16x8*)dst = u.v;
}

// ---------------------------------------------------------------------------
// K2 (fused prep+rh): per block = 16 tokens, 512 threads (8 waves), grid 512.
// ---------------------------------------------------------------------------
__global__ __launch_bounds__(512) void prep2_kernel(
    const float* __restrict__ x, const float* __restrict__ Wr,
    const __hip_bfloat16* __restrict__ Ab,
    const int* __restrict__ topk_p, __hip_bfloat16* __restrict__ Xc)
{
    __shared__ __align__(16) char smem[81920];
    __hip_bfloat16* xb = (__hip_bfloat16*)smem;      // [16][2048] bf16, swizzled
    float* stage = (float*)(smem + 65536);           // 16KB: Wr chunk staging
    float* red = (float*)smem;                       // overlay: [8][16][64] f32
    float* wf  = (float*)(smem + 65536);             // overlay: [16][16] f32

    const int tid = threadIdx.x;
    const int wave = tid >> 6, lane = tid & 63;
    const int qm = lane & 15, quad = lane >> 4;
    const int t0 = blockIdx.x * 16;
    const int tA = t0 + wave * 2;                    // wave owns 2 tokens

    float acc[NE][2];
#pragma unroll
    for (int e = 0; e < NE; ++e) { acc[e][0] = 0.f; acc[e][1] = 0.f; }

    const float4* x4 = (const float4*)x;
    float4 xv[2], xn[2];
    xv[0] = x4[(size_t)tA * 512 + lane];
    xv[1] = x4[(size_t)(tA + 1) * 512 + lane];

    // ---- phase 1: 8 K-chunks of 256 floats ----
    for (int c = 0; c < 8; ++c) {
        async_ld16(Wr + (size_t)wave * D_IN + c * 256 + lane * 4,
                   (void*)(stage + wave * 256));
        async_ld16(Wr + (size_t)(wave + 8) * D_IN + c * 256 + lane * 4,
                   (void*)(stage + (wave + 8) * 256));
        if (c < 7) {
            xn[0] = x4[(size_t)tA * 512 + (c + 1) * 64 + lane];
            xn[1] = x4[(size_t)(tA + 1) * 512 + (c + 1) * 64 + lane];
        }
        __syncthreads();

#pragma unroll
        for (int t = 0; t < 2; ++t) {
            const int tl = wave * 2 + t;
            union { short4 v; __hip_bfloat16 h[4]; } u;
            u.h[0] = __float2bfloat16(xv[t].x); u.h[1] = __float2bfloat16(xv[t].y);
            u.h[2] = __float2bfloat16(xv[t].z); u.h[3] = __float2bfloat16(xv[t].w);
            *(short4*)(Xc + (size_t)(t0 + tl) * KTOT + c * 256 + lane * 4) = u.v;
            const int gg = c * 32 + (lane >> 1);
            const int pg = gg ^ (tl & 7);
            *(short4*)((char*)xb + tl * 4096 + pg * 16 + (lane & 1) * 8) = u.v;
        }
        const float4* wr4 = (const float4*)stage;
#pragma unroll
        for (int e = 0; e < NE; ++e) {
            const float4 wv = wr4[e * 64 + lane];
            acc[e][0] += xv[0].x*wv.x + xv[0].y*wv.y + xv[0].z*wv.z + xv[0].w*wv.w;
            acc[e][1] += xv[1].x*wv.x + xv[1].y*wv.y + xv[1].z*wv.z + xv[1].w*wv.w;
        }
        __syncthreads();
        if (c < 7) { xv[0] = xn[0]; xv[1] = xn[1]; }
    }

    // ---- router reduce + softmax/top-k -> wf ----
#pragma unroll
    for (int off = 32; off; off >>= 1)
#pragma unroll
        for (int e = 0; e < NE; ++e) {
            acc[e][0] += __shfl_xor(acc[e][0], off, 64);
            acc[e][1] += __shfl_xor(acc[e][1], off, 64);
        }
    if (lane < 2) {
        const int tt = lane;
        const int k = topk_p[0];
        float m = -1e30f;
#pragma unroll
        for (int e = 0; e < NE; ++e) m = fmaxf(m, acc[e][tt]);
        float w[NE]; float ssum = 0.f;
#pragma unroll
        for (int e = 0; e < NE; ++e) { w[e] = __expf(acc[e][tt] - m); ssum += w[e]; }
        const float inv = 1.f / ssum;
#pragma unroll
        for (int e = 0; e < NE; ++e) w[e] *= inv;
        float* wfout = wf + (size_t)(wave * 2 + tt) * NE;
        if (k > 0 && k < NE) {
            int chosen[NE];
#pragma unroll
            for (int e = 0; e < NE; ++e) chosen[e] = 0;
            float ksum = 0.f;
            for (int it = 0; it < k; ++it) {
                int bi = 0; float bv = -1.f;
                for (int e = 0; e < NE; ++e)
                    if (!chosen[e] && w[e] > bv) { bv = w[e]; bi = e; }
                chosen[bi] = 1; ksum += bv;
            }
            const float rinv = 1.f / (ksum + 1e-6f);
            for (int e = 0; e < NE; ++e) wfout[e] = chosen[e] ? w[e] * rinv : 0.f;
        } else {
            for (int e = 0; e < NE; ++e) wfout[e] = w[e];
        }
    }

    // ---- phase 2: RH MFMA; wave w covers K slice [w*256, w*256+256) ----
    f32x4 racc[4] = {};
    const int kb = wave * 256;
#pragma unroll
    for (int s = 0; s < 4; ++s) {
        const int k0 = kb + s * 64;
        const int gg0 = (k0 >> 3) + quad;
        const bf16x8 a0 = *(const bf16x8*)((char*)xb + qm * 4096 + ((gg0 ^ (qm & 7)) * 16));
        const bf16x8 a1 = *(const bf16x8*)((char*)xb + qm * 4096 + (((gg0 + 4) ^ (qm & 7)) * 16));
        bf16x8 b0[4], b1[4];
#pragma unroll
        for (int nf = 0; nf < 4; ++nf) {
            const __hip_bfloat16* bp = Ab + (size_t)(qm + nf * 16) * D_IN + k0 + quad * 8;
            b0[nf] = *(const bf16x8*)bp;
            b1[nf] = *(const bf16x8*)(bp + 32);
        }
#pragma unroll
        for (int nf = 0; nf < 4; ++nf) {
            racc[nf] = __builtin_amdgcn_mfma_f32_16x16x32_bf16(a0, b0[nf], racc[nf], 0, 0, 0);
            racc[nf] = __builtin_amdgcn_mfma_f32_16x16x32_bf16(a1, b1[nf], racc[nf], 0, 0, 0);
        }
    }
    __syncthreads();

#pragma unroll
    for (int nf = 0; nf < 4; ++nf)
#pragma unroll
        for (int r = 0; r < 4; ++r)
            red[(wave * 16 + quad * 4 + r) * 64 + nf * 16 + qm] = racc[nf][r];
    __syncthreads();

#pragma unroll
    for (int it = 0; it < 4; ++it) {
        const int s = it * 512 + tid;
        const int t = s >> 7;
        const int chunk = s & 127;
        const int e = chunk >> 3, r0 = (chunk & 7) * 8;
        const float wgt = wf[t * 16 + e];
        float4 s0 = {0.f, 0.f, 0.f, 0.f}, s1 = {0.f, 0.f, 0.f, 0.f};
#pragma unroll
        for (int w2 = 0; w2 < 8; ++w2) {
            const float4 p0 = ((const float4*)red)[(w2 * 16 + t) * 16 + (r0 >> 2)];
            const float4 p1 = ((const float4*)red)[(w2 * 16 + t) * 16 + (r0 >> 2) + 1];
            s0.x += p0.x; s0.y += p0.y; s0.z += p0.z; s0.w += p0.w;
            s1.x += p1.x; s1.y += p1.y; s1.z += p1.z; s1.w += p1.w;
        }
        union { bf16x8 v; __hip_bfloat16 h[8]; } u;
        u.h[0] = __float2bfloat16(wgt * s0.x); u.h[1] = __float2bfloat16(wgt * s0.y);
        u.h[2] = __float2bfloat16(wgt * s0.z); u.h[3] = __float2bfloat16(wgt * s0.w);
        u.h[4] = __float2bfloat16(wgt * s1.x); u.h[5] = __float2bfloat16(wgt * s1.y);
        u.h[6] = __float2bfloat16(wgt * s1.z); u.h[7] = __float2bfloat16(wgt * s1.w);
        *(bf16x8*)(Xc + (size_t)(t0 + t) * KTOT + D_IN + chunk * 8) = u.v;
    }
}

// ---------------------------------------------------------------------------
// K4 v3: 256x256 tile, mfma_f32_32x32x16_bf16 (2x LDS arithmetic intensity
// vs 16x16x32 -> per-wave LDS read 24 KB/K-tile instead of 48: the R4
// kernel was LDS-BW-bound at 36% MfmaUtil). 512 thr / 8 waves (2M x 4N),
// per-wave output 128x64 = 4x2 32x32 tiles. B-frags loaded once per K-tile
// and carried in regs across both phases; A-frags once per phase.
// 2 phases/K-tile: {ds_reads; issue staging; 16 MFMA (setprio); counted
// vmcnt(8); barrier}. Staging split P1 = A-h0+B (6 ld), P2 = A-h1 (2 ld),
// each issued 2 phases before use; waits never drain to 0 in the loop.
// LDS content granule-XOR swizzled via pre-swizzled global source.
// ---------------------------------------------------------------------------
#define LDA3(BUF, M, ks) (*(const bf16x8*)(smem + (BUF) + \
    ((((M) >> 1) * 128 + wm2 * 64 + ((M) & 1) * 32 + l31) * 128) + \
    (((((ks) * 2 + lhi) ^ (l31 & 7))) << 4)))
#define LDB3(BUF, N, ks) (*(const bf16x8*)(smem + 65536 + (BUF) + \
    ((wn4 * 64 + (N) * 32 + l31) * 128) + \
    (((((ks) * 2 + lhi) ^ (l31 & 7))) << 4)))

#define GP(BUF, MH, ISSUE, WAIT) do { \
    bf16x8 af[2][4]; \
    if ((MH) == 0) { \
        _Pragma("unroll") for (int n = 0; n < 2; ++n) \
        _Pragma("unroll") for (int ks = 0; ks < 4; ++ks) \
            bfr[n][ks] = LDB3(BUF, n, ks); \
    } \
    _Pragma("unroll") for (int m = 0; m < 2; ++m) \
    _Pragma("unroll") for (int ks = 0; ks < 4; ++ks) \
        af[m][ks] = LDA3(BUF, (MH) * 2 + m, ks); \
    ISSUE; \
    __builtin_amdgcn_s_setprio(1); \
    _Pragma("unroll") for (int ks = 0; ks < 4; ++ks) \
    _Pragma("unroll") for (int m = 0; m < 2; ++m) \
    _Pragma("unroll") for (int n = 0; n < 2; ++n) \
        acc[(MH) * 2 + m][n] = __builtin_amdgcn_mfma_f32_32x32x16_bf16( \
            af[m][ks], bfr[n][ks], acc[(MH) * 2 + m][n], 0, 0, 0); \
    __builtin_amdgcn_s_setprio(0); \
    WAIT; \
    __builtin_amdgcn_sched_barrier(0); \
    __builtin_amdgcn_s_barrier(); \
    __builtin_amdgcn_sched_barrier(0); \
} while (0)

__global__ __launch_bounds__(512, 2) void gemm3_kernel(
    const __hip_bfloat16* __restrict__ Am,
    const __hip_bfloat16* __restrict__ Bm,
    const float* __restrict__ bias,
    float* __restrict__ C)
{
    __shared__ __align__(16) char smem[131072];   // A:[2][256][64] B:+64KB
    const int tid = threadIdx.x;
    const int w = tid >> 6, lane = tid & 63;
    const int l31 = lane & 31, lhi = lane >> 5;
    const int wm2 = w >> 2, wn4 = w & 3;

    int flat = blockIdx.y * gridDim.x + blockIdx.x;
    flat = (flat & 7) * 32 + (flat >> 3);
    const int bm = flat & 31, bn = flat >> 5;

    // staging source (pre-swizzled: granule g_src = g ^ (row&7))
    const int rb0 = w * 16 + (lane >> 3);
    const int rb1 = rb0 + 8;
    const int gs0 = (lane & 7) ^ (rb0 & 7);
    const int gs1 = (lane & 7) ^ (rb1 & 7);
    const __hip_bfloat16* pA0 = Am + (size_t)(bm * 256 + rb0) * KTOT + gs0 * 8;
    const __hip_bfloat16* pA1 = Am + (size_t)(bm * 256 + rb1) * KTOT + gs1 * 8;
    const __hip_bfloat16* pB0 = Bm + (size_t)(bn * 256 + rb0) * KTOT + gs0 * 8;
    const __hip_bfloat16* pB1 = Bm + (size_t)(bn * 256 + rb1) * KTOT + gs1 * 8;
    const size_t HO = (size_t)128 * KTOT;   // half-tile (128 rows) source offset

    f32x16 acc[4][2] = {};
    bf16x8 bfr[2][4];

    // P1(t): A-h0 (2 loads) + B both halves (4 loads)
    auto stageP1 = [&](int tn) {
        const size_t ko = (size_t)tn * 64;
        char* da = smem + (tn & 1) * 32768 + w * 2048;
        async_ld16(pA0 + ko, da);
        async_ld16(pA1 + ko, da + 1024);
        char* db = smem + 65536 + (tn & 1) * 32768 + w * 2048;
        async_ld16(pB0 + ko, db);
        async_ld16(pB1 + ko, db + 1024);
        async_ld16(pB0 + HO + ko, db + 16384);
        async_ld16(pB1 + HO + ko, db + 16384 + 1024);
    };
    // P2(t): A-h1 (2 loads)
    auto stageP2 = [&](int tn) {
        const size_t ko = (size_t)tn * 64;
        char* da = smem + (tn & 1) * 32768 + 16384 + w * 2048;
        async_ld16(pA0 + HO + ko, da);
        async_ld16(pA1 + HO + ko, da + 1024);
    };

    // prologue: queue = [P1(0):6, P2(0):2, P1(1):6] -> vmcnt(8) drains P1(0)
    stageP1(0); stageP2(0); stageP1(1);
    asm volatile("s_waitcnt vmcnt(8)" ::: "memory");
    __builtin_amdgcn_sched_barrier(0);
    __builtin_amdgcn_s_barrier();
    __builtin_amdgcn_sched_barrier(0);

    for (int t = 0; t < NTILE - 2; ++t) {
        const int bo = (t & 1) * 32768;
        GP(bo, 0, stageP2(t + 1),
           asm volatile("s_waitcnt vmcnt(8)" ::: "memory"));
        GP(bo, 1, stageP1(t + 2),
           asm volatile("s_waitcnt vmcnt(8)" ::: "memory"));
    }
    {   // t = NTILE-2
        const int bo = ((NTILE - 2) & 1) * 32768;
        GP(bo, 0, stageP2(NTILE - 1),
           asm volatile("s_waitcnt vmcnt(8)" ::: "memory"));
        GP(bo, 1, ,
           asm volatile("s_waitcnt vmcnt(2)" ::: "memory"));
    }
    {   // t = NTILE-1
        const int bo = ((NTILE - 1) & 1) * 32768;
        GP(bo, 0, ,
           asm volatile("s_waitcnt vmcnt(0)" ::: "memory"));
        GP(bo, 1, , );
    }

    // epilogue: C = acc + bias.  C/D 32x32: col=lane&31,
    // row=(reg&3)+8*(reg>>2)+4*(lane>>5)
#pragma unroll
    for (int n = 0; n < 2; ++n) {
        const int col = bn * 256 + wn4 * 64 + n * 32 + l31;
        const float bbv = bias[col];
#pragma unroll
        for (int m = 0; m < 4; ++m) {
            const size_t rbase = (size_t)bm * 256 + (m >> 1) * 128 + wm2 * 64
                               + (m & 1) * 32 + 4 * lhi;
#pragma unroll
            for (int reg = 0; reg < 16; ++reg) {
                const size_t row = rbase + (reg & 3) + 8 * (reg >> 2);
                C[row * D_OUT + col] = acc[m][n][reg] + bbv;
            }
        }
    }
}

extern "C" void kernel_launch(void* const* d_in, const int* in_sizes, int n_in,
                              void* d_out, int out_size, void* d_ws, size_t ws_size,
                              hipStream_t stream) {
    const float* x    = (const float*)d_in[0];
    const float* Wb   = (const float*)d_in[1];
    const float* bb   = (const float*)d_in[2];
    const float* A    = (const float*)d_in[3];
    const float* Bm   = (const float*)d_in[4];
    const float* Wr   = (const float*)d_in[5];
    const int*   topk = (const int*)d_in[6];
    float* out = (float*)d_out;
    const int T = in_sizes[0] / D_IN;   // 8192 tokens

    __hip_bfloat16* Xc = (__hip_bfloat16*)d_ws;                                 // T*KTOT bf16 (48MB)
    __hip_bfloat16* Wc = (__hip_bfloat16*)((char*)d_ws + (size_t)T * KTOT * 2); // D_OUT*KTOT bf16 (12MB)
    // Parked in d_out (fully overwritten by the final GEMM):
    __hip_bfloat16* Ab = (__hip_bfloat16*)d_out;              // 256 KB at front

    castwa_kernel<<<D_OUT + RNK, 384, 0, stream>>>(Wb, Bm, A, Wc, Ab);
    prep2_kernel<<<T / 16, 512, 0, stream>>>(x, Wr, Ab, topk, Xc);
    gemm3_kernel<<<dim3(32, 8), 512, 0, stream>>>(Xc, Wc, bb, out);
}

// Round 6
// 263.380 us; speedup vs baseline: 1.1607x; 1.0080x over previous
//
#include <hip/hip_runtime.h>
#include <hip/hip_bf16.h>

#define D_IN  2048
#define D_OUT 2048
#define RNK   64
#define NE    16
#define KTOT  3072   // D_IN + NE*RNK
#define NTILE 48     // KTOT / 64

typedef __attribute__((ext_vector_type(8))) short bf16x8;
typedef __attribute__((ext_vector_type(4))) float f32x4;
typedef __attribute__((ext_vector_type(16))) float f32x16;

__device__ __forceinline__ void async_ld16(const void* g, void* l) {
    __builtin_amdgcn_global_load_lds(
        (const __attribute__((address_space(1))) void*)g,
        (__attribute__((address_space(3))) void*)l,
        16, 0, 0);
}

// ---------------------------------------------------------------------------
// K1: merged weight prep.
//  blocks [0,2048):   Wc row n = [ W_base | B' ], B'[n][e*64+r] = B[e][n][r]
//  blocks [2048,2112): Ab row r = bf16(A[r])  (parked in d_out)
// ---------------------------------------------------------------------------
__global__ __launch_bounds__(384) void castwa_kernel(
    const float* __restrict__ Wb, const float* __restrict__ Bm,
    const float* __restrict__ A,
    __hip_bfloat16* __restrict__ Wc, __hip_bfloat16* __restrict__ Ab)
{
    const int c = threadIdx.x * 8;
    const float* src;
    __hip_bfloat16* dst;
    if (blockIdx.x < D_OUT) {
        const int n = blockIdx.x;
        if (c < D_IN) {
            src = Wb + (size_t)n * D_IN + c;
        } else {
            const int j = c - D_IN;
            const int e = j >> 6, r = j & 63;
            src = Bm + ((size_t)e * D_OUT + n) * RNK + r;
        }
        dst = Wc + (size_t)n * KTOT + c;
    } else {
        if (c >= D_IN) return;
        const int r = blockIdx.x - D_OUT;
        src = A + (size_t)r * D_IN + c;
        dst = Ab + (size_t)r * D_IN + c;
    }
    const float4 a = *(const float4*)src;
    const float4 b = *(const float4*)(src + 4);
    const float vv[8] = {a.x, a.y, a.z, a.w, b.x, b.y, b.z, b.w};
    union { bf16x8 v; __hip_bfloat16 h[8]; } u;
#pragma unroll
    for (int q = 0; q < 8; ++q) u.h[q] = __float2bfloat16(vv[q]);
    *(bf16x8*)dst = u.v;
}

// ---------------------------------------------------------------------------
// K2 v4 (fused prep+rh): 16 tokens/block, 512 thr (8 waves), grid 512.
// Phase 1 now counted-vmcnt pipelined (the R3-R5 version serialized a full
// L2 round trip at EVERY chunk barrier via the implicit vmcnt(0) drain of
// __syncthreads): 16 chunks of 128 floats, Wr stage double-buffered 2x8KB,
// ONE raw s_barrier per chunk preceded by vmcnt(1) (own stage done; next
// chunk's stage + x prefetch stay in flight). Lanes 0-31 = token 2w,
// lanes 32-63 = token 2w+1. Stage granules bank-swizzled on BOTH sides
// (src granule l31 ^ ((l31>>3)&7)) so the 16 float4 stage reads/chunk are
// conflict-free. LDS 64KB xb + 2x8KB stage = 80KB -> 2 blocks/CU.
// Phase 2 (RH MFMA from xb + global Ab) and epilogue unchanged from R5.
// ---------------------------------------------------------------------------
__global__ __launch_bounds__(512) void prep2_kernel(
    const float* __restrict__ x, const float* __restrict__ Wr,
    const __hip_bfloat16* __restrict__ Ab,
    const int* __restrict__ topk_p, __hip_bfloat16* __restrict__ Xc)
{
    __shared__ __align__(16) char smem[81920];
    __hip_bfloat16* xb = (__hip_bfloat16*)smem;      // [16][2048] bf16, swizzled
    float* stg = (float*)(smem + 65536);             // [2][16][128] f32 dbuf
    float* red = (float*)smem;                       // overlay: [8][16][64] f32
    float* wf  = (float*)(smem + 65536);             // overlay: [16][16] f32

    const int tid = threadIdx.x;
    const int wave = tid >> 6, lane = tid & 63;
    const int l31 = lane & 31, lh = lane >> 5;
    const int qm = lane & 15, quad = lane >> 4;
    const int t0 = blockIdx.x * 16;
    const int tl = wave * 2 + lh;                    // local token 0..15
    const size_t myt = (size_t)t0 + tl;

    float acc[NE];
#pragma unroll
    for (int e = 0; e < NE; ++e) acc[e] = 0.f;

    const float4* x4 = (const float4*)x;
    // bank-spread stage granule: bijection on 0..31, low3 mixed with high2
    const int sg = l31 ^ ((l31 >> 3) & 7);
    // staging source: wave w stages Wr rows 2w (lanes<32), 2w+1 (lanes>=32);
    // one async_ld16 = 1024B LDS (row pair), per-lane swizzled global src.
    const float* wr_src = Wr + (size_t)tl * D_IN + sg * 4;

    // prologue: stage chunk 0 (buf 0) + load x chunk 0
    async_ld16(wr_src, (void*)(stg + wave * 256));
    float4 xv = x4[myt * 512 + l31];
    float4 xn;

    for (int c = 0; c < 16; ++c) {
        // own S(c) complete (oldest); S(c+1)/x(c+1) not yet issued
        asm volatile("s_waitcnt vmcnt(1)" ::: "memory");
        __builtin_amdgcn_sched_barrier(0);
        __builtin_amdgcn_s_barrier();   // all waves' S(c) visible; buf^1 free
        __builtin_amdgcn_sched_barrier(0);
        if (c < 15) {
            async_ld16(wr_src + (c + 1) * 128,
                       (void*)(stg + ((c + 1) & 1) * 2048 + wave * 256));
            xn = x4[myt * 512 + (c + 1) * 32 + l31];
        }
        // ---- compute chunk c ----
        union { short4 v; __hip_bfloat16 h[4]; } u;
        u.h[0] = __float2bfloat16(xv.x); u.h[1] = __float2bfloat16(xv.y);
        u.h[2] = __float2bfloat16(xv.z); u.h[3] = __float2bfloat16(xv.w);
        *(short4*)(Xc + myt * KTOT + c * 128 + l31 * 4) = u.v;
        const int G = c * 16 + (l31 >> 1);           // 16B granule index
        *(short4*)((char*)xb + tl * 4096 + ((G ^ (tl & 7)) * 16)
                   + (l31 & 1) * 8) = u.v;
        const float* sb = stg + (c & 1) * 2048;
#pragma unroll
        for (int e = 0; e < NE; ++e) {
            const float4 wv = *(const float4*)(sb + e * 128 + sg * 4);
            acc[e] += xv.x * wv.x + xv.y * wv.y + xv.z * wv.z + xv.w * wv.w;
        }
        if (c < 15) xv = xn;
    }

    // ---- router reduce (within 32-lane halves) + softmax/top-k -> wf ----
#pragma unroll
    for (int off = 16; off; off >>= 1)
#pragma unroll
        for (int e = 0; e < NE; ++e)
            acc[e] += __shfl_xor(acc[e], off, 64);
    if (l31 == 0) {
        const int k = topk_p[0];
        float m = -1e30f;
#pragma unroll
        for (int e = 0; e < NE; ++e) m = fmaxf(m, acc[e]);
        float w[NE]; float ssum = 0.f;
#pragma unroll
        for (int e = 0; e < NE; ++e) { w[e] = __expf(acc[e] - m); ssum += w[e]; }
        const float inv = 1.f / ssum;
#pragma unroll
        for (int e = 0; e < NE; ++e) w[e] *= inv;
        float* wfout = wf + (size_t)tl * NE;         // overlays stg buf0 (dead)
        if (k > 0 && k < NE) {
            int chosen[NE];
#pragma unroll
            for (int e = 0; e < NE; ++e) chosen[e] = 0;
            float ksum = 0.f;
            for (int it = 0; it < k; ++it) {
                int bi = 0; float bv = -1.f;
                for (int e = 0; e < NE; ++e)
                    if (!chosen[e] && w[e] > bv) { bv = w[e]; bi = e; }
                chosen[bi] = 1; ksum += bv;
            }
            const float rinv = 1.f / (ksum + 1e-6f);
            for (int e = 0; e < NE; ++e) wfout[e] = chosen[e] ? w[e] * rinv : 0.f;
        } else {
            for (int e = 0; e < NE; ++e) wfout[e] = w[e];
        }
    }
    __syncthreads();   // xb + wf visible to all waves

    // ---- phase 2: RH MFMA; wave w covers K slice [w*256, w*256+256) ----
    f32x4 racc[4] = {};
    const int kb = wave * 256;
#pragma unroll
    for (int s = 0; s < 4; ++s) {
        const int k0 = kb + s * 64;
        const int gg0 = (k0 >> 3) + quad;
        const bf16x8 a0 = *(const bf16x8*)((char*)xb + qm * 4096 + ((gg0 ^ (qm & 7)) * 16));
        const bf16x8 a1 = *(const bf16x8*)((char*)xb + qm * 4096 + (((gg0 + 4) ^ (qm & 7)) * 16));
        bf16x8 b0[4], b1[4];
#pragma unroll
        for (int nf = 0; nf < 4; ++nf) {
            const __hip_bfloat16* bp = Ab + (size_t)(qm + nf * 16) * D_IN + k0 + quad * 8;
            b0[nf] = *(const bf16x8*)bp;
            b1[nf] = *(const bf16x8*)(bp + 32);
        }
#pragma unroll
        for (int nf = 0; nf < 4; ++nf) {
            racc[nf] = __builtin_amdgcn_mfma_f32_16x16x32_bf16(a0, b0[nf], racc[nf], 0, 0, 0);
            racc[nf] = __builtin_amdgcn_mfma_f32_16x16x32_bf16(a1, b1[nf], racc[nf], 0, 0, 0);
        }
    }
    __syncthreads();   // all xb reads done -> safe to overlay red on xb

#pragma unroll
    for (int nf = 0; nf < 4; ++nf)
#pragma unroll
        for (int r = 0; r < 4; ++r)
            red[(wave * 16 + quad * 4 + r) * 64 + nf * 16 + qm] = racc[nf][r];
    __syncthreads();

#pragma unroll
    for (int it = 0; it < 4; ++it) {
        const int s = it * 512 + tid;
        const int t = s >> 7;
        const int chunk = s & 127;
        const int e = chunk >> 3, r0 = (chunk & 7) * 8;
        const float wgt = wf[t * 16 + e];
        float4 s0 = {0.f, 0.f, 0.f, 0.f}, s1 = {0.f, 0.f, 0.f, 0.f};
#pragma unroll
        for (int w2 = 0; w2 < 8; ++w2) {
            const float4 p0 = ((const float4*)red)[(w2 * 16 + t) * 16 + (r0 >> 2)];
            const float4 p1 = ((const float4*)red)[(w2 * 16 + t) * 16 + (r0 >> 2) + 1];
            s0.x += p0.x; s0.y += p0.y; s0.z += p0.z; s0.w += p0.w;
            s1.x += p1.x; s1.y += p1.y; s1.z += p1.z; s1.w += p1.w;
        }
        union { bf16x8 v; __hip_bfloat16 h[8]; } u;
        u.h[0] = __float2bfloat16(wgt * s0.x); u.h[1] = __float2bfloat16(wgt * s0.y);
        u.h[2] = __float2bfloat16(wgt * s0.z); u.h[3] = __float2bfloat16(wgt * s0.w);
        u.h[4] = __float2bfloat16(wgt * s1.x); u.h[5] = __float2bfloat16(wgt * s1.y);
        u.h[6] = __float2bfloat16(wgt * s1.z); u.h[7] = __float2bfloat16(wgt * s1.w);
        *(bf16x8*)(Xc + (size_t)(t0 + t) * KTOT + D_IN + chunk * 8) = u.v;
    }
}

// ---------------------------------------------------------------------------
// K4 v3b: 256x256 tile, mfma_f32_32x32x16_bf16 (R5), with 2D XCD mapping:
// XCD x owns an 8bm x 4bn sub-grid (A 12MB + B 6MB per L2 instead of
// streaming all 48MB of A through every XCD -> FETCH 202MB should drop).
// ---------------------------------------------------------------------------
#define LDA3(BUF, M, ks) (*(const bf16x8*)(smem + (BUF) + \
    ((((M) >> 1) * 128 + wm2 * 64 + ((M) & 1) * 32 + l31) * 128) + \
    (((((ks) * 2 + lhi) ^ (l31 & 7))) << 4)))
#define LDB3(BUF, N, ks) (*(const bf16x8*)(smem + 65536 + (BUF) + \
    ((wn4 * 64 + (N) * 32 + l31) * 128) + \
    (((((ks) * 2 + lhi) ^ (l31 & 7))) << 4)))

#define GP(BUF, MH, ISSUE, WAIT) do { \
    bf16x8 af[2][4]; \
    if ((MH) == 0) { \
        _Pragma("unroll") for (int n = 0; n < 2; ++n) \
        _Pragma("unroll") for (int ks = 0; ks < 4; ++ks) \
            bfr[n][ks] = LDB3(BUF, n, ks); \
    } \
    _Pragma("unroll") for (int m = 0; m < 2; ++m) \
    _Pragma("unroll") for (int ks = 0; ks < 4; ++ks) \
        af[m][ks] = LDA3(BUF, (MH) * 2 + m, ks); \
    ISSUE; \
    __builtin_amdgcn_s_setprio(1); \
    _Pragma("unroll") for (int ks = 0; ks < 4; ++ks) \
    _Pragma("unroll") for (int m = 0; m < 2; ++m) \
    _Pragma("unroll") for (int n = 0; n < 2; ++n) \
        acc[(MH) * 2 + m][n] = __builtin_amdgcn_mfma_f32_32x32x16_bf16( \
            af[m][ks], bfr[n][ks], acc[(MH) * 2 + m][n], 0, 0, 0); \
    __builtin_amdgcn_s_setprio(0); \
    WAIT; \
    __builtin_amdgcn_sched_barrier(0); \
    __builtin_amdgcn_s_barrier(); \
    __builtin_amdgcn_sched_barrier(0); \
} while (0)

__global__ __launch_bounds__(512, 2) void gemm3_kernel(
    const __hip_bfloat16* __restrict__ Am,
    const __hip_bfloat16* __restrict__ Bm,
    const float* __restrict__ bias,
    float* __restrict__ C)
{
    __shared__ __align__(16) char smem[131072];   // A:[2][256][64] B:+64KB
    const int tid = threadIdx.x;
    const int w = tid >> 6, lane = tid & 63;
    const int l31 = lane & 31, lhi = lane >> 5;
    const int wm2 = w >> 2, wn4 = w & 3;

    // 2D XCD map: xcd = flat&7 owns bm in [(xcd&3)*8,+8), bn in [(xcd>>2)*4,+4)
    const int flat = blockIdx.y * gridDim.x + blockIdx.x;
    const int xcd = flat & 7, j = flat >> 3;
    const int bm = (xcd & 3) * 8 + (j & 7);
    const int bn = (xcd >> 2) * 4 + (j >> 3);

    // staging source (pre-swizzled: granule g_src = g ^ (row&7))
    const int rb0 = w * 16 + (lane >> 3);
    const int rb1 = rb0 + 8;
    const int gs0 = (lane & 7) ^ (rb0 & 7);
    const int gs1 = (lane & 7) ^ (rb1 & 7);
    const __hip_bfloat16* pA0 = Am + (size_t)(bm * 256 + rb0) * KTOT + gs0 * 8;
    const __hip_bfloat16* pA1 = Am + (size_t)(bm * 256 + rb1) * KTOT + gs1 * 8;
    const __hip_bfloat16* pB0 = Bm + (size_t)(bn * 256 + rb0) * KTOT + gs0 * 8;
    const __hip_bfloat16* pB1 = Bm + (size_t)(bn * 256 + rb1) * KTOT + gs1 * 8;
    const size_t HO = (size_t)128 * KTOT;   // half-tile (128 rows) source offset

    f32x16 acc[4][2] = {};
    bf16x8 bfr[2][4];

    auto stageP1 = [&](int tn) {
        const size_t ko = (size_t)tn * 64;
        char* da = smem + (tn & 1) * 32768 + w * 2048;
        async_ld16(pA0 + ko, da);
        async_ld16(pA1 + ko, da + 1024);
        char* db = smem + 65536 + (tn & 1) * 32768 + w * 2048;
        async_ld16(pB0 + ko, db);
        async_ld16(pB1 + ko, db + 1024);
        async_ld16(pB0 + HO + ko, db + 16384);
        async_ld16(pB1 + HO + ko, db + 16384 + 1024);
    };
    auto stageP2 = [&](int tn) {
        const size_t ko = (size_t)tn * 64;
        char* da = smem + (tn & 1) * 32768 + 16384 + w * 2048;
        async_ld16(pA0 + HO + ko, da);
        async_ld16(pA1 + HO + ko, da + 1024);
    };

    stageP1(0); stageP2(0); stageP1(1);
    asm volatile("s_waitcnt vmcnt(8)" ::: "memory");
    __builtin_amdgcn_sched_barrier(0);
    __builtin_amdgcn_s_barrier();
    __builtin_amdgcn_sched_barrier(0);

    for (int t = 0; t < NTILE - 2; ++t) {
        const int bo = (t & 1) * 32768;
        GP(bo, 0, stageP2(t + 1),
           asm volatile("s_waitcnt vmcnt(8)" ::: "memory"));
        GP(bo, 1, stageP1(t + 2),
           asm volatile("s_waitcnt vmcnt(8)" ::: "memory"));
    }
    {   // t = NTILE-2
        const int bo = ((NTILE - 2) & 1) * 32768;
        GP(bo, 0, stageP2(NTILE - 1),
           asm volatile("s_waitcnt vmcnt(8)" ::: "memory"));
        GP(bo, 1, ,
           asm volatile("s_waitcnt vmcnt(2)" ::: "memory"));
    }
    {   // t = NTILE-1
        const int bo = ((NTILE - 1) & 1) * 32768;
        GP(bo, 0, ,
           asm volatile("s_waitcnt vmcnt(0)" ::: "memory"));
        GP(bo, 1, , );
    }

    // epilogue: C = acc + bias.  C/D 32x32: col=lane&31,
    // row=(reg&3)+8*(reg>>2)+4*(lane>>5)
#pragma unroll
    for (int n = 0; n < 2; ++n) {
        const int col = bn * 256 + wn4 * 64 + n * 32 + l31;
        const float bbv = bias[col];
#pragma unroll
        for (int m = 0; m < 4; ++m) {
            const size_t rbase = (size_t)bm * 256 + (m >> 1) * 128 + wm2 * 64
                               + (m & 1) * 32 + 4 * lhi;
#pragma unroll
            for (int reg = 0; reg < 16; ++reg) {
                const size_t row = rbase + (reg & 3) + 8 * (reg >> 2);
                C[row * D_OUT + col] = acc[m][n][reg] + bbv;
            }
        }
    }
}

extern "C" void kernel_launch(void* const* d_in, const int* in_sizes, int n_in,
                              void* d_out, int out_size, void* d_ws, size_t ws_size,
                              hipStream_t stream) {
    const float* x    = (const float*)d_in[0];
    const float* Wb   = (const float*)d_in[1];
    const float* bb   = (const float*)d_in[2];
    const float* A    = (const float*)d_in[3];
    const float* Bm   = (const float*)d_in[4];
    const float* Wr   = (const float*)d_in[5];
    const int*   topk = (const int*)d_in[6];
    float* out = (float*)d_out;
    const int T = in_sizes[0] / D_IN;   // 8192 tokens

    __hip_bfloat16* Xc = (__hip_bfloat16*)d_ws;                                 // T*KTOT bf16 (48MB)
    __hip_bfloat16* Wc = (__hip_bfloat16*)((char*)d_ws + (size_t)T * KTOT * 2); // D_OUT*KTOT bf16 (12MB)
    // Parked in d_out (fully overwritten by the final GEMM):
    __hip_bfloat16* Ab = (__hip_bfloat16*)d_out;              // 256 KB at front

    castwa_kernel<<<D_OUT + RNK, 384, 0, stream>>>(Wb, Bm, A, Wc, Ab);
    prep2_kernel<<<T / 16, 512, 0, stream>>>(x, Wr, Ab, topk, Xc);
    gemm3_kernel<<<dim3(32, 8), 512, 0, stream>>>(Xc, Wc, bb, out);
}